// Round 5
// baseline (195.906 us; speedup 1.0000x reference)
//
#include <hip/hip_runtime.h>
#include <hip/hip_bf16.h>
#include <hip/hip_cooperative_groups.h>

namespace cg = cooperative_groups;

// B=1024, K(conf)=256, D=1024, P=768.
// SINGLE cooperative dispatch, 256 blocks x 256 threads (1 block/CU):
//   phase0 prep -> sync -> phase1 q|km -> sync -> phase2 scores -> sync
//   -> phase3 softmax+out.  Round-4-verified phase bodies.

typedef __attribute__((ext_vector_type(8))) short short8;   // 8 bf16
typedef __attribute__((ext_vector_type(4))) float f32x4;    // MFMA acc

__device__ __forceinline__ ushort f2bf(float x) {
    union { float f; uint u; } c; c.f = x;
    return (ushort)((c.u + 0x7FFFu + ((c.u >> 16) & 1u)) >> 16);  // RNE
}
__device__ __forceinline__ float bflo(uint u) {     // bf16 bits in LOW half
    union { uint u; float f; } c; c.u = u << 16; return c.f;
}
__device__ __forceinline__ float bfhi(uint u) {     // bf16 bits in HIGH half
    union { uint u; float f; } c; c.u = u & 0xFFFF0000u; return c.f;
}

struct GemmTiles {
    __align__(16) ushort As[64][72];
    __align__(16) ushort Bs[64][72];
};
struct OutTiles {
    __align__(16) ushort At[64][264];   // exp(scores) bf16, K=256 + pad
    __align__(16) ushort Bs[64][72];
    float rowInv[64];
};
union SharedU {
    float     tr[32][33];   // prep transpose staging
    GemmTiles g;            // 18.4 KB
    OutTiles  o;            // 43.3 KB  (union size)
};

// 64x64 NT GEMM core (round-4 verified): C_bf16 = scale * A[64,K] @ B[64,K]^T
__device__ __forceinline__
void gemm64_core(GemmTiles& S, const ushort* __restrict__ A,
                 const ushort* __restrict__ B, ushort* __restrict__ Cb,
                 int m0, int n0, int N, int K, float scale)
{
    const int t = threadIdx.x;
    const int wave = t >> 6, lane = t & 63;
    const int wm = (wave >> 1) * 32, wn = (wave & 1) * 32;
    const int lrow = lane & 15, lko = (lane >> 4) * 8;

    f32x4 acc[2][2];
    #pragma unroll
    for (int i = 0; i < 2; ++i)
        #pragma unroll
        for (int j = 0; j < 2; ++j) acc[i][j] = (f32x4)0.0f;

    const int sr = t >> 2, sk = (t & 3) << 4;
    const ushort* Ap = A + (size_t)(m0 + sr) * K + sk;
    const ushort* Bp = B + (size_t)(n0 + sr) * K + sk;

    uint4 av0 = *(const uint4*)(Ap);
    uint4 av1 = *(const uint4*)(Ap + 8);
    uint4 bv0 = *(const uint4*)(Bp);
    uint4 bv1 = *(const uint4*)(Bp + 8);

    for (int k0 = 0; k0 < K; k0 += 64) {
        *(uint4*)&S.As[sr][sk]     = av0;
        *(uint4*)&S.As[sr][sk + 8] = av1;
        *(uint4*)&S.Bs[sr][sk]     = bv0;
        *(uint4*)&S.Bs[sr][sk + 8] = bv1;
        __syncthreads();
        if (k0 + 64 < K) {
            av0 = *(const uint4*)(Ap + k0 + 64);
            av1 = *(const uint4*)(Ap + k0 + 72);
            bv0 = *(const uint4*)(Bp + k0 + 64);
            bv1 = *(const uint4*)(Bp + k0 + 72);
        }
        #pragma unroll
        for (int kk = 0; kk < 64; kk += 32) {
            const short8 a0 = *(const short8*)&S.As[wm + lrow][kk + lko];
            const short8 a1 = *(const short8*)&S.As[wm + 16 + lrow][kk + lko];
            const short8 b0 = *(const short8*)&S.Bs[wn + lrow][kk + lko];
            const short8 b1 = *(const short8*)&S.Bs[wn + 16 + lrow][kk + lko];
            acc[0][0] = __builtin_amdgcn_mfma_f32_16x16x32_bf16(a0, b0, acc[0][0], 0, 0, 0);
            acc[0][1] = __builtin_amdgcn_mfma_f32_16x16x32_bf16(a0, b1, acc[0][1], 0, 0, 0);
            acc[1][0] = __builtin_amdgcn_mfma_f32_16x16x32_bf16(a1, b0, acc[1][0], 0, 0, 0);
            acc[1][1] = __builtin_amdgcn_mfma_f32_16x16x32_bf16(a1, b1, acc[1][1], 0, 0, 0);
        }
        __syncthreads();
    }

    const int quad = lane >> 4;  // D: row=(lane>>4)*4+reg, col=lane&15
    #pragma unroll
    for (int i = 0; i < 2; ++i)
        #pragma unroll
        for (int j = 0; j < 2; ++j)
            #pragma unroll
            for (int r = 0; r < 4; ++r) {
                const int m = m0 + wm + i * 16 + quad * 4 + r;
                const int n = n0 + wn + j * 16 + lrow;
                Cb[(size_t)m * N + n] = f2bf(acc[i][j][r] * scale);
            }
}

__global__ __launch_bounds__(256)
void ccim_fused(const float* __restrict__ J, const float* __restrict__ conf,
                const float* __restrict__ prior, const float* __restrict__ Wq,
                const float* __restrict__ Wk,
                ushort* __restrict__ Jb, ushort* __restrict__ confb,
                ushort* __restrict__ WqT, ushort* __restrict__ WkT,
                ushort* __restrict__ cpT, ushort* __restrict__ qb,
                ushort* __restrict__ kmb, ushort* __restrict__ scb,
                float* __restrict__ out)
{
    __shared__ SharedU S;
    const int t = threadIdx.x;
    const int bid = blockIdx.x;
    cg::grid_group grid = cg::this_grid();

    // ================= phase 0: prep (bf16 operands) =================
    {
        // flat converts: J (262144 float4) then conf (65536 float4)
        const int gtid = bid * 256 + t;
        #pragma unroll 1
        for (int u = gtid; u < 327680; u += 65536) {
            const float* src; ushort* dst; int e;
            if (u < 262144) { src = J;    dst = Jb;    e = u * 4; }
            else            { src = conf; dst = confb; e = (u - 262144) * 4; }
            const float4 v = *(const float4*)(src + e);
            ushort4 o;
            o.x = f2bf(v.x); o.y = f2bf(v.y); o.z = f2bf(v.z); o.w = f2bf(v.w);
            *(ushort4*)(dst + e) = o;
        }
        // 32x32 transposes: Wq (768 tiles) | Wk (768) | conf*prior -> cpT (256)
        #pragma unroll 1
        for (int tb = bid; tb < 1792; tb += 256) {
            const float* src; ushort* dst; int R, C, rt, ct; bool useP;
            if (tb < 768)       { src = Wq;   dst = WqT; R = 1024; C = 768;  rt = tb / 24;          ct = tb % 24;          useP = false; }
            else if (tb < 1536) { const int b2 = tb - 768;  src = Wk;   dst = WkT; R = 1024; C = 768;  rt = b2 / 24; ct = b2 % 24; useP = false; }
            else                { const int b2 = tb - 1536; src = conf; dst = cpT; R = 256;  C = 1024; rt = b2 / 32; ct = b2 % 32; useP = true;  }
            {
                const int row = t >> 3, c4 = (t & 7) << 2;
                const float4 v = *(const float4*)(src + (size_t)(rt * 32 + row) * C + ct * 32 + c4);
                const float p = useP ? prior[rt * 32 + row] : 1.0f;
                S.tr[row][c4 + 0] = v.x * p; S.tr[row][c4 + 1] = v.y * p;
                S.tr[row][c4 + 2] = v.z * p; S.tr[row][c4 + 3] = v.w * p;
            }
            __syncthreads();
            {
                const int orow = t >> 3, oc4 = (t & 7) << 2;
                ushort4 o;
                o.x = f2bf(S.tr[oc4 + 0][orow]); o.y = f2bf(S.tr[oc4 + 1][orow]);
                o.z = f2bf(S.tr[oc4 + 2][orow]); o.w = f2bf(S.tr[oc4 + 3][orow]);
                *(ushort4*)(dst + (size_t)(ct * 32 + orow) * R + rt * 32 + oc4) = o;
            }
            __syncthreads();
        }
    }
    grid.sync();

    // ================= phase 1: q = Jb@WqT^T | km = confb@WkT^T =================
    if (bid < 240) {
        const ushort *A, *B; ushort* C; int b2 = bid;
        if (b2 < 192) { A = Jb; B = WqT; C = qb; }
        else          { b2 -= 192; A = confb; B = WkT; C = kmb; }
        gemm64_core(S.g, A, B, C, (b2 / 12) * 64, (b2 % 12) * 64, 768, 1024, 1.0f);
    }
    grid.sync();

    // ================= phase 2: scores = qb@kmb^T / 32 =================
    if (bid < 64) {
        gemm64_core(S.g, qb, kmb, scb, (bid >> 2) * 64, (bid & 3) * 64, 256, 768, 0.03125f);
    }
    grid.sync();

    // ================= phase 3: out = J + softmax(scores) @ cpT^T =================
    {
        const int m0 = (bid >> 4) * 64, n0 = (bid & 15) * 64;

        // softmax prologue: 4 threads/row, unnormalized exp -> LDS (bf16)
        {
            const int row = t >> 2;
            const int cb  = (t & 3) * 64;
            const ushort* srow = scb + (size_t)(m0 + row) * 256 + cb;
            uint4 s[8];
            #pragma unroll
            for (int i = 0; i < 8; ++i) s[i] = *(const uint4*)(srow + i * 8);

            float mx = -1e30f;
            #pragma unroll
            for (int i = 0; i < 8; ++i) {
                mx = fmaxf(mx, fmaxf(fmaxf(bflo(s[i].x), bfhi(s[i].x)),
                                     fmaxf(bflo(s[i].y), bfhi(s[i].y))));
                mx = fmaxf(mx, fmaxf(fmaxf(bflo(s[i].z), bfhi(s[i].z)),
                                     fmaxf(bflo(s[i].w), bfhi(s[i].w))));
            }
            mx = fmaxf(mx, __shfl_xor(mx, 1));
            mx = fmaxf(mx, __shfl_xor(mx, 2));

            float sum = 0.0f;
            #pragma unroll
            for (int i = 0; i < 8; ++i) {
                uint4 o;
                uint* su = (uint*)&s[i];
                uint* ou = (uint*)&o;
                #pragma unroll
                for (int w = 0; w < 4; ++w) {
                    const ushort e0 = f2bf(__expf(bflo(su[w]) - mx));
                    const ushort e1 = f2bf(__expf(bfhi(su[w]) - mx));
                    sum += bflo((uint)e0) + bflo((uint)e1);   // single shift (r4 fix)
                    ou[w] = (uint)e0 | ((uint)e1 << 16);
                }
                *(uint4*)&S.o.At[row][cb + i * 8] = o;
            }
            sum += __shfl_xor(sum, 1);
            sum += __shfl_xor(sum, 2);
            if ((t & 3) == 0) S.o.rowInv[row] = 1.0f / sum;
        }
        __syncthreads();

        // GEMM: out_tile = expS[64,256] @ cpT_tile[64,256]^T
        const int wave = t >> 6, lane = t & 63;
        const int wm = (wave >> 1) * 32, wn = (wave & 1) * 32;
        const int lrow = lane & 15, lko = (lane >> 4) * 8;

        f32x4 acc[2][2];
        #pragma unroll
        for (int i = 0; i < 2; ++i)
            #pragma unroll
            for (int j = 0; j < 2; ++j) acc[i][j] = (f32x4)0.0f;

        const int sr = t >> 2, sk = (t & 3) << 4;
        const ushort* Bp = cpT + (size_t)(n0 + sr) * 256 + sk;
        uint4 bv0 = *(const uint4*)(Bp);
        uint4 bv1 = *(const uint4*)(Bp + 8);

        for (int k0 = 0; k0 < 256; k0 += 64) {
            *(uint4*)&S.o.Bs[sr][sk]     = bv0;
            *(uint4*)&S.o.Bs[sr][sk + 8] = bv1;
            __syncthreads();
            if (k0 + 64 < 256) {
                bv0 = *(const uint4*)(Bp + k0 + 64);
                bv1 = *(const uint4*)(Bp + k0 + 72);
            }
            #pragma unroll
            for (int kk = 0; kk < 64; kk += 32) {
                const short8 a0 = *(const short8*)&S.o.At[wm + lrow][k0 + kk + lko];
                const short8 a1 = *(const short8*)&S.o.At[wm + 16 + lrow][k0 + kk + lko];
                const short8 b0 = *(const short8*)&S.o.Bs[wn + lrow][kk + lko];
                const short8 b1 = *(const short8*)&S.o.Bs[wn + 16 + lrow][kk + lko];
                acc[0][0] = __builtin_amdgcn_mfma_f32_16x16x32_bf16(a0, b0, acc[0][0], 0, 0, 0);
                acc[0][1] = __builtin_amdgcn_mfma_f32_16x16x32_bf16(a0, b1, acc[0][1], 0, 0, 0);
                acc[1][0] = __builtin_amdgcn_mfma_f32_16x16x32_bf16(a1, b0, acc[1][0], 0, 0, 0);
                acc[1][1] = __builtin_amdgcn_mfma_f32_16x16x32_bf16(a1, b1, acc[1][1], 0, 0, 0);
            }
            __syncthreads();
        }

        const int quad = lane >> 4;
        #pragma unroll
        for (int i = 0; i < 2; ++i)
            #pragma unroll
            for (int j = 0; j < 2; ++j)
                #pragma unroll
                for (int r = 0; r < 4; ++r) {
                    const int mrel = wm + i * 16 + quad * 4 + r;
                    const int m = m0 + mrel;
                    const int n = n0 + wn + j * 16 + lrow;
                    const size_t off = (size_t)m * 1024 + n;
                    out[off] = acc[i][j][r] * S.o.rowInv[mrel] + J[off];
                }
    }
}

extern "C" void kernel_launch(void* const* d_in, const int* in_sizes, int n_in,
                              void* d_out, int out_size, void* d_ws, size_t ws_size,
                              hipStream_t stream)
{
    const float* J     = (const float*)d_in[0];
    const float* conf  = (const float*)d_in[1];
    const float* prior = (const float*)d_in[2];
    const float* Wq    = (const float*)d_in[3];
    const float* Wk    = (const float*)d_in[4];
    float* out = (float*)d_out;

    ushort* ws = (ushort*)d_ws;
    ushort* Jb    = ws;                  // 1024*1024
    ushort* confb = Jb    + 1048576;     // 256*1024
    ushort* WqT   = confb + 262144;      // 768*1024
    ushort* WkT   = WqT   + 786432;      // 768*1024
    ushort* cpT   = WkT   + 786432;      // 1024*256
    ushort* qb    = cpT   + 262144;      // 1024*768
    ushort* kmb   = qb    + 786432;      // 256*768
    ushort* scb   = kmb   + 196608;      // 1024*256 bf16 scores

    void* args[] = { &J, &conf, &prior, &Wq, &Wk,
                     &Jb, &confb, &WqT, &WkT, &cpT, &qb, &kmb, &scb, &out };
    hipLaunchCooperativeKernel((void*)ccim_fused, dim3(256), dim3(256),
                               args, 0, stream);
}

// Round 6
// 131.820 us; speedup vs baseline: 1.4862x; 1.4862x over previous
//
#include <hip/hip_runtime.h>
#include <hip/hip_bf16.h>

// B=1024, K(conf)=256, D=1024, P=768.
// TWO launches (grid.sync measured ~30us/sync on 8-XCD — abandoned):
//  L1 (496 blocks): qk GEMM w/ on-the-fly fp32->bf16 staging  +  cpT transpose
//  L2 (64 blocks):  fused scores(+q rows staged)+softmax+out, m-split 16 rows

typedef __attribute__((ext_vector_type(8))) short short8;   // 8 bf16
typedef __attribute__((ext_vector_type(4))) float f32x4;    // MFMA acc

__device__ __forceinline__ ushort f2bf(float x) {           // RNE (epilogues)
    union { float f; uint u; } c; c.f = x;
    return (ushort)((c.u + 0x7FFFu + ((c.u >> 16) & 1u)) >> 16);
}
__device__ __forceinline__ uint fbits(float x) {
    union { float f; uint u; } c; c.f = x; return c.u;
}
// pack two fp32 -> bf16 pair (lo = first), round-half-up (2 VALU ops/elem)
__device__ __forceinline__ uint pk_rhu(float lo, float hi) {
    return ((fbits(lo) + 0x8000u) >> 16) | ((fbits(hi) + 0x8000u) & 0xFFFF0000u);
}

#define MFMA_BF16 __builtin_amdgcn_mfma_f32_16x16x32_bf16

// ===========================================================================
// L1: blocks 0..239: q = J@Wq (192) | km = conf@Wk (48), fp32 inputs,
//     bf16 conversion fused into LDS staging. B operand is NN [k][n].
//     blocks 240..495: cpT[d][k] = bf16(conf[k][d] * prior[k])  (verified r2)
// ===========================================================================
union Lds1 {
    float tr[32][33];
    struct {
        __align__(16) ushort As[64][72];   // As[m][k]
        __align__(16) ushort Bs[64][72];   // Bs[n][k]
    } g;
};

__global__ __launch_bounds__(256)
void l1_kernel(const float* __restrict__ J, const float* __restrict__ conf,
               const float* __restrict__ prior, const float* __restrict__ Wq,
               const float* __restrict__ Wk, ushort* __restrict__ qb,
               ushort* __restrict__ kmb, ushort* __restrict__ cpT)
{
    __shared__ Lds1 S;
    const int t = threadIdx.x;
    const int bid = blockIdx.x;

    if (bid >= 240) {   // ---- cpT transpose (256 tiles of 32x32) ----
        const int b2 = bid - 240;
        const int rt = b2 >> 5, ct = b2 & 31;     // rt: 8 row-tiles, ct: 32 col-tiles
        {
            const int row = t >> 3, c4 = (t & 7) << 2;
            const float4 v = *(const float4*)(conf + (size_t)(rt * 32 + row) * 1024 + ct * 32 + c4);
            const float p = prior[rt * 32 + row];
            S.tr[row][c4 + 0] = v.x * p; S.tr[row][c4 + 1] = v.y * p;
            S.tr[row][c4 + 2] = v.z * p; S.tr[row][c4 + 3] = v.w * p;
        }
        __syncthreads();
        {
            const int orow = t >> 3, oc4 = (t & 7) << 2;
            ushort4 o;
            o.x = f2bf(S.tr[oc4 + 0][orow]); o.y = f2bf(S.tr[oc4 + 1][orow]);
            o.z = f2bf(S.tr[oc4 + 2][orow]); o.w = f2bf(S.tr[oc4 + 3][orow]);
            *(ushort4*)(cpT + (size_t)(ct * 32 + orow) * 256 + rt * 32 + oc4) = o;
        }
        return;
    }

    // ---- qk GEMM ----
    const float *A, *Bm; ushort* C; int m0, n0;
    if (bid < 192) { A = J;    Bm = Wq; C = qb;  m0 = (bid / 12) * 64; n0 = (bid % 12) * 64; }
    else { const int b2 = bid - 192;
           A = conf; Bm = Wk; C = kmb; m0 = (b2  / 12) * 64; n0 = (b2  % 12) * 64; }

    const int wave = t >> 6, lane = t & 63;
    const int wm = (wave >> 1) * 32, wn = (wave & 1) * 32;
    const int lrow = lane & 15, quad = lane >> 4, lko = quad * 8;

    f32x4 acc[2][2];
    #pragma unroll
    for (int i = 0; i < 2; ++i)
        #pragma unroll
        for (int j = 0; j < 2; ++j) acc[i][j] = (f32x4)0.0f;

    // staging maps: A: 64 rows x 64 k (thread: row sr, k-quarter q4, 16 floats)
    //               B: NN [k][n] -> Bs[n][k]; thread: n-quad bn, k-pairs bk,bk+1 / bk+32,bk+33
    const int sr = t >> 2, q4 = (t & 3) << 4;
    const int bn = (t & 15) << 2, bk = (t >> 4) << 1;
    const float* Ap = A + (size_t)(m0 + sr) * 1024 + q4;
    const float* Bp = Bm + (size_t)bk * 768 + n0 + bn;

    float4 aF0 = *(const float4*)(Ap + 0),  aF1 = *(const float4*)(Ap + 4);
    float4 aF2 = *(const float4*)(Ap + 8),  aF3 = *(const float4*)(Ap + 12);
    float4 bF0 = *(const float4*)(Bp);
    float4 bF1 = *(const float4*)(Bp + 768);
    float4 bF2 = *(const float4*)(Bp + (size_t)32 * 768);
    float4 bF3 = *(const float4*)(Bp + (size_t)33 * 768);

    for (int k0 = 0; k0 < 1024; k0 += 64) {
        // ---- convert + write LDS
        {
            uint2 w;
            w.x = pk_rhu(aF0.x, aF0.y); w.y = pk_rhu(aF0.z, aF0.w);
            *(uint2*)&S.g.As[sr][q4 + 0] = w;
            w.x = pk_rhu(aF1.x, aF1.y); w.y = pk_rhu(aF1.z, aF1.w);
            *(uint2*)&S.g.As[sr][q4 + 4] = w;
            w.x = pk_rhu(aF2.x, aF2.y); w.y = pk_rhu(aF2.z, aF2.w);
            *(uint2*)&S.g.As[sr][q4 + 8] = w;
            w.x = pk_rhu(aF3.x, aF3.y); w.y = pk_rhu(aF3.z, aF3.w);
            *(uint2*)&S.g.As[sr][q4 + 12] = w;
            // B: pack (k, k+1) pairs -> one b32 per n
            *(uint*)&S.g.Bs[bn + 0][bk]      = pk_rhu(bF0.x, bF1.x);
            *(uint*)&S.g.Bs[bn + 1][bk]      = pk_rhu(bF0.y, bF1.y);
            *(uint*)&S.g.Bs[bn + 2][bk]      = pk_rhu(bF0.z, bF1.z);
            *(uint*)&S.g.Bs[bn + 3][bk]      = pk_rhu(bF0.w, bF1.w);
            *(uint*)&S.g.Bs[bn + 0][bk + 32] = pk_rhu(bF2.x, bF3.x);
            *(uint*)&S.g.Bs[bn + 1][bk + 32] = pk_rhu(bF2.y, bF3.y);
            *(uint*)&S.g.Bs[bn + 2][bk + 32] = pk_rhu(bF2.z, bF3.z);
            *(uint*)&S.g.Bs[bn + 3][bk + 32] = pk_rhu(bF2.w, bF3.w);
        }
        __syncthreads();
        if (k0 + 64 < 1024) {   // prefetch next step
            aF0 = *(const float4*)(Ap + k0 + 64);
            aF1 = *(const float4*)(Ap + k0 + 68);
            aF2 = *(const float4*)(Ap + k0 + 72);
            aF3 = *(const float4*)(Ap + k0 + 76);
            const float* Bn = Bp + (size_t)(k0 + 64) * 768;
            bF0 = *(const float4*)(Bn);
            bF1 = *(const float4*)(Bn + 768);
            bF2 = *(const float4*)(Bn + (size_t)32 * 768);
            bF3 = *(const float4*)(Bn + (size_t)33 * 768);
        }
        #pragma unroll
        for (int kk = 0; kk < 64; kk += 32) {
            const short8 a0 = *(const short8*)&S.g.As[wm + lrow][kk + lko];
            const short8 a1 = *(const short8*)&S.g.As[wm + 16 + lrow][kk + lko];
            const short8 b0 = *(const short8*)&S.g.Bs[wn + lrow][kk + lko];
            const short8 b1 = *(const short8*)&S.g.Bs[wn + 16 + lrow][kk + lko];
            acc[0][0] = MFMA_BF16(a0, b0, acc[0][0], 0, 0, 0);
            acc[0][1] = MFMA_BF16(a0, b1, acc[0][1], 0, 0, 0);
            acc[1][0] = MFMA_BF16(a1, b0, acc[1][0], 0, 0, 0);
            acc[1][1] = MFMA_BF16(a1, b1, acc[1][1], 0, 0, 0);
        }
        __syncthreads();
    }

    // epilogue (verified layout: row = quad*4+reg, col = lane&15)
    #pragma unroll
    for (int i = 0; i < 2; ++i)
        #pragma unroll
        for (int j = 0; j < 2; ++j)
            #pragma unroll
            for (int r = 0; r < 4; ++r) {
                const int m = m0 + wm + i * 16 + quad * 4 + r;
                const int n = n0 + wn + j * 16 + lrow;
                C[(size_t)m * 768 + n] = f2bf(acc[i][j][r]);
            }
}

// ===========================================================================
// L2: 64 blocks x 16 rows. scores = q@km^T/32 (q staged in LDS, km b-frags
// direct from global) -> softmax (fp32 in LDS) -> out = J + attn@cpT^T
// (attn bf16 in LDS as A-operand, cpT b-frags direct from global).
// ===========================================================================
struct Lds2 {
    __align__(16) ushort Aq[16][776];   // q rows bf16 (24.8 KB)
    __align__(16) float  sc[16][260];   // scores fp32 (16.6 KB)
    __align__(16) ushort At[16][264];   // exp(scores) bf16 (8.4 KB)
    float rowInv[16];
};

__global__ __launch_bounds__(256)
void l2_kernel(const ushort* __restrict__ qb, const ushort* __restrict__ kmb,
               const ushort* __restrict__ cpT, const float* __restrict__ J,
               float* __restrict__ out)
{
    __shared__ Lds2 S;
    const int t = threadIdx.x;
    const int m0 = blockIdx.x * 16;
    const int wave = t >> 6, lane = t & 63;
    const int lrow = lane & 15, quad = lane >> 4, lko = quad * 8;

    // ---- stage q rows once: 16 x 768 bf16 = 1536 uint4
    #pragma unroll
    for (int i = 0; i < 6; ++i) {
        const int idx = i * 256 + t;
        const int row = idx / 96, c = idx % 96;
        *(uint4*)&S.Aq[row][c * 8] =
            *(const uint4*)(qb + (size_t)(m0 + row) * 768 + c * 8);
    }
    __syncthreads();

    // ---- phase A: scores[16, 64w..64w+63], K=768
    {
        f32x4 acc[4];
        #pragma unroll
        for (int j = 0; j < 4; ++j) acc[j] = (f32x4)0.0f;
        const ushort* kmBase = kmb + (size_t)(wave * 64 + lrow) * 768 + lko;

        for (int c = 0; c < 12; ++c) {
            const int k0 = c * 64;
            const short8 a0 = *(const short8*)&S.Aq[lrow][k0 + lko];
            const short8 a1 = *(const short8*)&S.Aq[lrow][k0 + 32 + lko];
            #pragma unroll
            for (int j = 0; j < 4; ++j) {
                const ushort* bp = kmBase + (size_t)(16 * j) * 768 + k0;
                const short8 b0 = *(const short8*)(bp);
                const short8 b1 = *(const short8*)(bp + 32);
                acc[j] = MFMA_BF16(a0, b0, acc[j], 0, 0, 0);
                acc[j] = MFMA_BF16(a1, b1, acc[j], 0, 0, 0);
            }
        }
        #pragma unroll
        for (int j = 0; j < 4; ++j)
            #pragma unroll
            for (int r = 0; r < 4; ++r)
                S.sc[quad * 4 + r][wave * 64 + 16 * j + lrow] = acc[j][r] * 0.03125f;
    }
    __syncthreads();

    // ---- softmax: 16 threads/row, 16 cols each; fp32 -> bf16 At + rowInv
    {
        const int row = t >> 4, seg = t & 15;
        float vv[16];
        #pragma unroll
        for (int u = 0; u < 4; ++u)
            *(float4*)&vv[u * 4] = *(const float4*)&S.sc[row][seg * 16 + u * 4];

        float mx = vv[0];
        #pragma unroll
        for (int i = 1; i < 16; ++i) mx = fmaxf(mx, vv[i]);
        mx = fmaxf(mx, __shfl_xor(mx, 1));
        mx = fmaxf(mx, __shfl_xor(mx, 2));
        mx = fmaxf(mx, __shfl_xor(mx, 4));
        mx = fmaxf(mx, __shfl_xor(mx, 8));

        float e[16], sum = 0.0f;
        #pragma unroll
        for (int i = 0; i < 16; ++i) { e[i] = __expf(vv[i] - mx); sum += e[i]; }

        uint p[8];
        #pragma unroll
        for (int i = 0; i < 8; ++i)
            p[i] = (uint)f2bf(e[2 * i]) | ((uint)f2bf(e[2 * i + 1]) << 16);
        *(uint4*)&S.At[row][seg * 16]     = make_uint4(p[0], p[1], p[2], p[3]);
        *(uint4*)&S.At[row][seg * 16 + 8] = make_uint4(p[4], p[5], p[6], p[7]);

        sum += __shfl_xor(sum, 1);
        sum += __shfl_xor(sum, 2);
        sum += __shfl_xor(sum, 4);
        sum += __shfl_xor(sum, 8);
        if (seg == 0) S.rowInv[row] = 1.0f / sum;
    }
    __syncthreads();

    // ---- phase B: out[16, 256w..256w+255] = J + attn @ cpT^T, K=256
    {
        short8 pa[8];
        #pragma unroll
        for (int kk = 0; kk < 8; ++kk)
            pa[kk] = *(const short8*)&S.At[lrow][kk * 32 + lko];

        const ushort* cpBase = cpT + (size_t)(wave * 256 + lrow) * 256 + lko;

        #pragma unroll 4
        for (int j = 0; j < 16; ++j) {
            f32x4 o = (f32x4)0.0f;
            const ushort* bp = cpBase + (size_t)(16 * j) * 256;
            #pragma unroll
            for (int kk = 0; kk < 8; ++kk) {
                const short8 b = *(const short8*)(bp + kk * 32);
                o = MFMA_BF16(pa[kk], b, o, 0, 0, 0);
            }
            const int n = wave * 256 + 16 * j + lrow;
            #pragma unroll
            for (int r = 0; r < 4; ++r) {
                const int mrel = quad * 4 + r;
                const size_t off = (size_t)(m0 + mrel) * 1024 + n;
                out[off] = o[r] * S.rowInv[mrel] + J[off];
            }
        }
    }
}

extern "C" void kernel_launch(void* const* d_in, const int* in_sizes, int n_in,
                              void* d_out, int out_size, void* d_ws, size_t ws_size,
                              hipStream_t stream)
{
    const float* J     = (const float*)d_in[0];
    const float* conf  = (const float*)d_in[1];
    const float* prior = (const float*)d_in[2];
    const float* Wq    = (const float*)d_in[3];
    const float* Wk    = (const float*)d_in[4];
    float* out = (float*)d_out;

    ushort* ws  = (ushort*)d_ws;
    ushort* qb  = ws;               // 1024*768
    ushort* kmb = qb  + 786432;     // 256*768
    ushort* cpT = kmb + 196608;     // 1024*256   (~2.5 MB total)

    l1_kernel<<<496, 256, 0, stream>>>(J, conf, prior, Wq, Wk, qb, kmb, cpT);
    l2_kernel<<<64, 256, 0, stream>>>(qb, kmb, cpT, J, out);
}

// Round 7
// 129.517 us; speedup vs baseline: 1.5126x; 1.0178x over previous
//
#include <hip/hip_runtime.h>
#include <hip/hip_bf16.h>

// B=1024, K(conf)=256, D=1024, P=768.
// TWO launches:
//  L1 (496 blocks): qk GEMM w/ on-the-fly fp32->bf16 staging + cpT transpose
//                   (unchanged, round-6 verified)
//  L2 (64 blocks):  fused scores+softmax+out, 16 rows/block.
//                   Round 6 lesson: per-lane global B-frag gathers in the MFMA
//                   loop serialize on latency (48.9us @ 0.6% util). Rewritten
//                   with cooperative LDS staging + register prefetch.

typedef __attribute__((ext_vector_type(8))) short short8;   // 8 bf16
typedef __attribute__((ext_vector_type(4))) float f32x4;    // MFMA acc

__device__ __forceinline__ ushort f2bf(float x) {           // RNE
    union { float f; uint u; } c; c.f = x;
    return (ushort)((c.u + 0x7FFFu + ((c.u >> 16) & 1u)) >> 16);
}
__device__ __forceinline__ uint fbits(float x) {
    union { float f; uint u; } c; c.f = x; return c.u;
}
// pack two fp32 -> bf16 pair (lo = first), round-half-up
__device__ __forceinline__ uint pk_rhu(float lo, float hi) {
    return ((fbits(lo) + 0x8000u) >> 16) | ((fbits(hi) + 0x8000u) & 0xFFFF0000u);
}

#define MFMA_BF16 __builtin_amdgcn_mfma_f32_16x16x32_bf16

// ===========================================================================
// L1 (unchanged from round 6 — passed)
// ===========================================================================
union Lds1 {
    float tr[32][33];
    struct {
        __align__(16) ushort As[64][72];   // As[m][k]
        __align__(16) ushort Bs[64][72];   // Bs[n][k]
    } g;
};

__global__ __launch_bounds__(256)
void l1_kernel(const float* __restrict__ J, const float* __restrict__ conf,
               const float* __restrict__ prior, const float* __restrict__ Wq,
               const float* __restrict__ Wk, ushort* __restrict__ qb,
               ushort* __restrict__ kmb, ushort* __restrict__ cpT)
{
    __shared__ Lds1 S;
    const int t = threadIdx.x;
    const int bid = blockIdx.x;

    if (bid >= 240) {   // ---- cpT transpose (256 tiles of 32x32) ----
        const int b2 = bid - 240;
        const int rt = b2 >> 5, ct = b2 & 31;
        {
            const int row = t >> 3, c4 = (t & 7) << 2;
            const float4 v = *(const float4*)(conf + (size_t)(rt * 32 + row) * 1024 + ct * 32 + c4);
            const float p = prior[rt * 32 + row];
            S.tr[row][c4 + 0] = v.x * p; S.tr[row][c4 + 1] = v.y * p;
            S.tr[row][c4 + 2] = v.z * p; S.tr[row][c4 + 3] = v.w * p;
        }
        __syncthreads();
        {
            const int orow = t >> 3, oc4 = (t & 7) << 2;
            ushort4 o;
            o.x = f2bf(S.tr[oc4 + 0][orow]); o.y = f2bf(S.tr[oc4 + 1][orow]);
            o.z = f2bf(S.tr[oc4 + 2][orow]); o.w = f2bf(S.tr[oc4 + 3][orow]);
            *(ushort4*)(cpT + (size_t)(ct * 32 + orow) * 256 + rt * 32 + oc4) = o;
        }
        return;
    }

    // ---- qk GEMM ----
    const float *A, *Bm; ushort* C; int m0, n0;
    if (bid < 192) { A = J;    Bm = Wq; C = qb;  m0 = (bid / 12) * 64; n0 = (bid % 12) * 64; }
    else { const int b2 = bid - 192;
           A = conf; Bm = Wk; C = kmb; m0 = (b2  / 12) * 64; n0 = (b2  % 12) * 64; }

    const int wave = t >> 6, lane = t & 63;
    const int wm = (wave >> 1) * 32, wn = (wave & 1) * 32;
    const int lrow = lane & 15, quad = lane >> 4, lko = quad * 8;

    f32x4 acc[2][2];
    #pragma unroll
    for (int i = 0; i < 2; ++i)
        #pragma unroll
        for (int j = 0; j < 2; ++j) acc[i][j] = (f32x4)0.0f;

    const int sr = t >> 2, q4 = (t & 3) << 4;
    const int bn = (t & 15) << 2, bk = (t >> 4) << 1;
    const float* Ap = A + (size_t)(m0 + sr) * 1024 + q4;
    const float* Bp = Bm + (size_t)bk * 768 + n0 + bn;

    float4 aF0 = *(const float4*)(Ap + 0),  aF1 = *(const float4*)(Ap + 4);
    float4 aF2 = *(const float4*)(Ap + 8),  aF3 = *(const float4*)(Ap + 12);
    float4 bF0 = *(const float4*)(Bp);
    float4 bF1 = *(const float4*)(Bp + 768);
    float4 bF2 = *(const float4*)(Bp + (size_t)32 * 768);
    float4 bF3 = *(const float4*)(Bp + (size_t)33 * 768);

    for (int k0 = 0; k0 < 1024; k0 += 64) {
        {
            uint2 w;
            w.x = pk_rhu(aF0.x, aF0.y); w.y = pk_rhu(aF0.z, aF0.w);
            *(uint2*)&S.g.As[sr][q4 + 0] = w;
            w.x = pk_rhu(aF1.x, aF1.y); w.y = pk_rhu(aF1.z, aF1.w);
            *(uint2*)&S.g.As[sr][q4 + 4] = w;
            w.x = pk_rhu(aF2.x, aF2.y); w.y = pk_rhu(aF2.z, aF2.w);
            *(uint2*)&S.g.As[sr][q4 + 8] = w;
            w.x = pk_rhu(aF3.x, aF3.y); w.y = pk_rhu(aF3.z, aF3.w);
            *(uint2*)&S.g.As[sr][q4 + 12] = w;
            *(uint*)&S.g.Bs[bn + 0][bk]      = pk_rhu(bF0.x, bF1.x);
            *(uint*)&S.g.Bs[bn + 1][bk]      = pk_rhu(bF0.y, bF1.y);
            *(uint*)&S.g.Bs[bn + 2][bk]      = pk_rhu(bF0.z, bF1.z);
            *(uint*)&S.g.Bs[bn + 3][bk]      = pk_rhu(bF0.w, bF1.w);
            *(uint*)&S.g.Bs[bn + 0][bk + 32] = pk_rhu(bF2.x, bF3.x);
            *(uint*)&S.g.Bs[bn + 1][bk + 32] = pk_rhu(bF2.y, bF3.y);
            *(uint*)&S.g.Bs[bn + 2][bk + 32] = pk_rhu(bF2.z, bF3.z);
            *(uint*)&S.g.Bs[bn + 3][bk + 32] = pk_rhu(bF2.w, bF3.w);
        }
        __syncthreads();
        if (k0 + 64 < 1024) {
            aF0 = *(const float4*)(Ap + k0 + 64);
            aF1 = *(const float4*)(Ap + k0 + 68);
            aF2 = *(const float4*)(Ap + k0 + 72);
            aF3 = *(const float4*)(Ap + k0 + 76);
            const float* Bn = Bp + (size_t)(k0 + 64) * 768;
            bF0 = *(const float4*)(Bn);
            bF1 = *(const float4*)(Bn + 768);
            bF2 = *(const float4*)(Bn + (size_t)32 * 768);
            bF3 = *(const float4*)(Bn + (size_t)33 * 768);
        }
        #pragma unroll
        for (int kk = 0; kk < 64; kk += 32) {
            const short8 a0 = *(const short8*)&S.g.As[wm + lrow][kk + lko];
            const short8 a1 = *(const short8*)&S.g.As[wm + 16 + lrow][kk + lko];
            const short8 b0 = *(const short8*)&S.g.Bs[wn + lrow][kk + lko];
            const short8 b1 = *(const short8*)&S.g.Bs[wn + 16 + lrow][kk + lko];
            acc[0][0] = MFMA_BF16(a0, b0, acc[0][0], 0, 0, 0);
            acc[0][1] = MFMA_BF16(a0, b1, acc[0][1], 0, 0, 0);
            acc[1][0] = MFMA_BF16(a1, b0, acc[1][0], 0, 0, 0);
            acc[1][1] = MFMA_BF16(a1, b1, acc[1][1], 0, 0, 0);
        }
        __syncthreads();
    }

    #pragma unroll
    for (int i = 0; i < 2; ++i)
        #pragma unroll
        for (int j = 0; j < 2; ++j)
            #pragma unroll
            for (int r = 0; r < 4; ++r) {
                const int m = m0 + wm + i * 16 + quad * 4 + r;
                const int n = n0 + wn + j * 16 + lrow;
                C[(size_t)m * 768 + n] = f2bf(acc[i][j][r]);
            }
}

// ===========================================================================
// L2: 64 blocks x 16 rows, LDS-staged throughout.
// ===========================================================================
struct PhaseA {
    __align__(16) ushort Aq[16][776];   // q rows bf16 (24.8 KB)
    __align__(16) ushort Bs[64][136];   // km k-chunk (17.4 KB)
};
struct PhaseB {
    __align__(16) ushort At[16][264];   // exp(scores) bf16 (8.4 KB)
    __align__(16) ushort Bs2[64][264];  // cpT chunk, full K=256 (33.8 KB)
};
union Lds2 { PhaseA a; PhaseB b; };     // 42.2 KB

__global__ __launch_bounds__(256)
void l2_kernel(const ushort* __restrict__ qb, const ushort* __restrict__ kmb,
               const ushort* __restrict__ cpT, const float* __restrict__ J,
               float* __restrict__ out)
{
    __shared__ Lds2 S;
    __shared__ float sc[16][260];       // fp32 scores (16.6 KB); total ~57.6 KB
    __shared__ float rowInv[16];

    const int t = threadIdx.x;
    const int m0 = blockIdx.x * 16;
    const int wave = t >> 6, lane = t & 63;
    const int lrow = lane & 15, quad = lane >> 4, lko = quad * 8;
    const int srow = t >> 2;            // cooperative staging row 0..63

    // ---- stage q rows once: 16 x 768 bf16
    #pragma unroll
    for (int i = 0; i < 6; ++i) {
        const int idx = i * 256 + t;
        const int row = idx / 96, c = idx % 96;
        *(uint4*)&S.a.Aq[row][c * 8] =
            *(const uint4*)(qb + (size_t)(m0 + row) * 768 + c * 8);
    }
    __syncthreads();

    // ---- phase A: scores = q @ km^T / 32, cooperative BK=128 staging
    {
        const int skc = (t & 3) * 32;   // 32 ushorts (64 B) per thread per step
        uint4 p0, p1, p2, p3;
        {
            const ushort* src = kmb + (size_t)srow * 768 + skc;   // chunk0, k0=0
            p0 = *(const uint4*)(src);      p1 = *(const uint4*)(src + 8);
            p2 = *(const uint4*)(src + 16); p3 = *(const uint4*)(src + 24);
        }
        f32x4 acc = (f32x4)0.0f;
        #pragma unroll 1
        for (int s = 0; s < 24; ++s) {          // 4 chunks x 6 k-steps
            const int c  = s / 6;
            const int k0 = (s % 6) * 128;
            *(uint4*)&S.a.Bs[srow][skc]      = p0;
            *(uint4*)&S.a.Bs[srow][skc + 8]  = p1;
            *(uint4*)&S.a.Bs[srow][skc + 16] = p2;
            *(uint4*)&S.a.Bs[srow][skc + 24] = p3;
            __syncthreads();
            if (s + 1 < 24) {                   // register prefetch next step
                const int c2 = (s + 1) / 6, k2 = ((s + 1) % 6) * 128;
                const ushort* src = kmb + (size_t)(c2 * 64 + srow) * 768 + k2 + skc;
                p0 = *(const uint4*)(src);      p1 = *(const uint4*)(src + 8);
                p2 = *(const uint4*)(src + 16); p3 = *(const uint4*)(src + 24);
            }
            #pragma unroll
            for (int kk = 0; kk < 4; ++kk) {
                const short8 a = *(const short8*)&S.a.Aq[lrow][k0 + kk * 32 + lko];
                const short8 b = *(const short8*)&S.a.Bs[wave * 16 + lrow][kk * 32 + lko];
                acc = MFMA_BF16(a, b, acc, 0, 0, 0);
            }
            __syncthreads();
            if ((s % 6) == 5) {                 // chunk done -> write scores
                #pragma unroll
                for (int r = 0; r < 4; ++r)
                    sc[quad * 4 + r][c * 64 + wave * 16 + lrow] = acc[r] * 0.03125f;
                acc = (f32x4)0.0f;
            }
        }
    }
    __syncthreads();

    // ---- softmax: 16 threads/row (round-6 verified); writes At + rowInv
    {
        const int row = t >> 4, seg = t & 15;
        float vv[16];
        #pragma unroll
        for (int u = 0; u < 4; ++u)
            *(float4*)&vv[u * 4] = *(const float4*)&sc[row][seg * 16 + u * 4];

        float mx = vv[0];
        #pragma unroll
        for (int i = 1; i < 16; ++i) mx = fmaxf(mx, vv[i]);
        mx = fmaxf(mx, __shfl_xor(mx, 1));
        mx = fmaxf(mx, __shfl_xor(mx, 2));
        mx = fmaxf(mx, __shfl_xor(mx, 4));
        mx = fmaxf(mx, __shfl_xor(mx, 8));

        float e[16], sum = 0.0f;
        #pragma unroll
        for (int i = 0; i < 16; ++i) { e[i] = __expf(vv[i] - mx); sum += e[i]; }

        uint p[8];
        #pragma unroll
        for (int i = 0; i < 8; ++i)
            p[i] = (uint)f2bf(e[2 * i]) | ((uint)f2bf(e[2 * i + 1]) << 16);
        *(uint4*)&S.b.At[row][seg * 16]     = make_uint4(p[0], p[1], p[2], p[3]);
        *(uint4*)&S.b.At[row][seg * 16 + 8] = make_uint4(p[4], p[5], p[6], p[7]);

        sum += __shfl_xor(sum, 1);
        sum += __shfl_xor(sum, 2);
        sum += __shfl_xor(sum, 4);
        sum += __shfl_xor(sum, 8);
        if (seg == 0) rowInv[row] = 1.0f / sum;
    }
    __syncthreads();

    // ---- phase B: out = J + attn @ cpT^T, 16 chunks of 64 cols, full K=256
    {
        short8 pa[8];
        #pragma unroll
        for (int kk = 0; kk < 8; ++kk)
            pa[kk] = *(const short8*)&S.b.At[lrow][kk * 32 + lko];

        const int skc = (t & 3) * 64;   // 64 ushorts (128 B) per thread per chunk
        uint4 q0, q1, q2, q3, q4, q5, q6, q7;
        {
            const ushort* src = cpT + (size_t)srow * 256 + skc;   // chunk 0
            q0 = *(const uint4*)(src);      q1 = *(const uint4*)(src + 8);
            q2 = *(const uint4*)(src + 16); q3 = *(const uint4*)(src + 24);
            q4 = *(const uint4*)(src + 32); q5 = *(const uint4*)(src + 40);
            q6 = *(const uint4*)(src + 48); q7 = *(const uint4*)(src + 56);
        }
        #pragma unroll 1
        for (int ch = 0; ch < 16; ++ch) {
            *(uint4*)&S.b.Bs2[srow][skc]      = q0;
            *(uint4*)&S.b.Bs2[srow][skc + 8]  = q1;
            *(uint4*)&S.b.Bs2[srow][skc + 16] = q2;
            *(uint4*)&S.b.Bs2[srow][skc + 24] = q3;
            *(uint4*)&S.b.Bs2[srow][skc + 32] = q4;
            *(uint4*)&S.b.Bs2[srow][skc + 40] = q5;
            *(uint4*)&S.b.Bs2[srow][skc + 48] = q6;
            *(uint4*)&S.b.Bs2[srow][skc + 56] = q7;
            __syncthreads();
            if (ch + 1 < 16) {
                const ushort* src = cpT + (size_t)((ch + 1) * 64 + srow) * 256 + skc;
                q0 = *(const uint4*)(src);      q1 = *(const uint4*)(src + 8);
                q2 = *(const uint4*)(src + 16); q3 = *(const uint4*)(src + 24);
                q4 = *(const uint4*)(src + 32); q5 = *(const uint4*)(src + 40);
                q6 = *(const uint4*)(src + 48); q7 = *(const uint4*)(src + 56);
            }
            const int n = ch * 64 + wave * 16 + lrow;
            float jv[4];
            #pragma unroll
            for (int r = 0; r < 4; ++r)                      // J prefetch
                jv[r] = J[(size_t)(m0 + quad * 4 + r) * 1024 + n];
            f32x4 o = (f32x4)0.0f;
            #pragma unroll
            for (int kk = 0; kk < 8; ++kk) {
                const short8 b = *(const short8*)&S.b.Bs2[wave * 16 + lrow][kk * 32 + lko];
                o = MFMA_BF16(pa[kk], b, o, 0, 0, 0);
            }
            #pragma unroll
            for (int r = 0; r < 4; ++r)
                out[(size_t)(m0 + quad * 4 + r) * 1024 + n] =
                    o[r] * rowInv[quad * 4 + r] + jv[r];
            __syncthreads();
        }
    }
}

extern "C" void kernel_launch(void* const* d_in, const int* in_sizes, int n_in,
                              void* d_out, int out_size, void* d_ws, size_t ws_size,
                              hipStream_t stream)
{
    const float* J     = (const float*)d_in[0];
    const float* conf  = (const float*)d_in[1];
    const float* prior = (const float*)d_in[2];
    const float* Wq    = (const float*)d_in[3];
    const float* Wk    = (const float*)d_in[4];
    float* out = (float*)d_out;

    ushort* ws  = (ushort*)d_ws;
    ushort* qb  = ws;               // 1024*768
    ushort* kmb = qb  + 786432;     // 256*768
    ushort* cpT = kmb + 196608;     // 1024*256   (~2.5 MB total)

    l1_kernel<<<496, 256, 0, stream>>>(J, conf, prior, Wq, Wk, qb, kmb, cpT);
    l2_kernel<<<64, 256, 0, stream>>>(qb, kmb, cpT, J, out);
}

// Round 8
// 96.970 us; speedup vs baseline: 2.0203x; 1.3356x over previous
//
#include <hip/hip_runtime.h>
#include <hip/hip_bf16.h>

// B=1024, K(conf)=256, D=1024, P=768.
// Round-4 structure (best measured: 95.8us), with:
//  - prep: flat bf16 conversion for Wq/Wk (NN layout, no LDS transpose)
//  - qk:   B staged from NN layout with k-pair packing (1 bit-op/word)
// scores/out kernels are round-4 verbatim (verified).

typedef __attribute__((ext_vector_type(8))) short short8;   // 8 bf16
typedef __attribute__((ext_vector_type(4))) float f32x4;    // MFMA acc

__device__ __forceinline__ ushort f2bf(float x) {           // RNE
    union { float f; uint u; } c; c.f = x;
    return (ushort)((c.u + 0x7FFFu + ((c.u >> 16) & 1u)) >> 16);
}
__device__ __forceinline__ float bflo(uint u) {     // bf16 bits in LOW half
    union { uint u; float f; } c; c.u = u << 16; return c.f;
}
__device__ __forceinline__ float bfhi(uint u) {     // bf16 bits in HIGH half
    union { uint u; float f; } c; c.u = u & 0xFFFF0000u; return c.f;
}

#define MFMA_BF16 __builtin_amdgcn_mfma_f32_16x16x32_bf16

// ---------------------------------------------------------------------------
// prep: blocks [0,1024) J->Jb, [1024,1280) conf->confb, [1280,2048) Wq->Wqb
// (flat NN), [2048,2816) Wk->Wkb (flat NN), [2816,3072) cpT transpose.
// ---------------------------------------------------------------------------
__global__ __launch_bounds__(256)
void prep_kernel(const float* __restrict__ J, const float* __restrict__ conf,
                 const float* __restrict__ prior, const float* __restrict__ Wq,
                 const float* __restrict__ Wk,
                 ushort* __restrict__ Jb, ushort* __restrict__ confb,
                 ushort* __restrict__ Wqb, ushort* __restrict__ Wkb,
                 ushort* __restrict__ cpT)
{
    const int t = threadIdx.x;
    int b = blockIdx.x;

    if (b < 2816) {  // flat convert, 1024 elems (256 x float4) per block
        const float* src; ushort* dst; int base;
        if (b < 1024)      { src = J;    dst = Jb;    base = b * 1024; }
        else if (b < 1280) { src = conf; dst = confb; base = (b - 1024) * 1024; }
        else if (b < 2048) { src = Wq;   dst = Wqb;   base = (b - 1280) * 1024; }
        else               { src = Wk;   dst = Wkb;   base = (b - 2048) * 1024; }
        const float4 v = *(const float4*)(src + base + t * 4);
        ushort4 o;
        o.x = f2bf(v.x); o.y = f2bf(v.y); o.z = f2bf(v.z); o.w = f2bf(v.w);
        *(ushort4*)(dst + base + t * 4) = o;
        return;
    }

    // cpT[d][k] = bf16(conf[k][d] * prior[k]) — 256 tiles of 32x32 (verified)
    __shared__ float tr[32][33];
    const int b2 = b - 2816;
    const int rt = b2 >> 5, ct = b2 & 31;
    {
        const int row = t >> 3, c4 = (t & 7) << 2;
        const float4 v = *(const float4*)(conf + (size_t)(rt * 32 + row) * 1024 + ct * 32 + c4);
        const float p = prior[rt * 32 + row];
        tr[row][c4 + 0] = v.x * p; tr[row][c4 + 1] = v.y * p;
        tr[row][c4 + 2] = v.z * p; tr[row][c4 + 3] = v.w * p;
    }
    __syncthreads();
    {
        const int orow = t >> 3, oc4 = (t & 7) << 2;
        ushort4 o;
        o.x = f2bf(tr[oc4 + 0][orow]); o.y = f2bf(tr[oc4 + 1][orow]);
        o.z = f2bf(tr[oc4 + 2][orow]); o.w = f2bf(tr[oc4 + 3][orow]);
        *(ushort4*)(cpT + (size_t)(ct * 32 + orow) * 256 + rt * 32 + oc4) = o;
    }
}

// ---------------------------------------------------------------------------
// qk: q = Jb @ Wqb (192 blocks) | km = confb @ Wkb (48 blocks).
// A: [M][1024] bf16 NT staging (round-4 verified).
// B: [1024][768] bf16 NN; Bs[n][k] built by k-pair packing (round-6-l1
//    verified addressing; from bf16 the pack is lossless: u0 | u1<<16).
// ---------------------------------------------------------------------------
__global__ __launch_bounds__(256)
void qk_kernel(const ushort* __restrict__ Jb, const ushort* __restrict__ Wqb,
               const ushort* __restrict__ confb, const ushort* __restrict__ Wkb,
               ushort* __restrict__ qb, ushort* __restrict__ kmb)
{
    __shared__ __align__(16) ushort As[64][72];
    __shared__ __align__(16) ushort Bs[64][72];

    const int t = threadIdx.x;
    int bid = blockIdx.x;
    const ushort *A, *Wb; ushort* C;
    if (bid < 192) { A = Jb; Wb = Wqb; C = qb; }
    else           { bid -= 192; A = confb; Wb = Wkb; C = kmb; }
    const int m0 = (bid / 12) * 64, n0 = (bid % 12) * 64;

    const int wave = t >> 6, lane = t & 63;
    const int wm = (wave >> 1) * 32, wn = (wave & 1) * 32;
    const int lrow = lane & 15, quad = lane >> 4, lko = quad * 8;

    f32x4 acc[2][2];
    #pragma unroll
    for (int i = 0; i < 2; ++i)
        #pragma unroll
        for (int j = 0; j < 2; ++j) acc[i][j] = (f32x4)0.0f;

    // A staging: row sr, 16 ushorts (2x uint4) at k-offset sk
    const int sr = t >> 2, sk = (t & 3) << 4;
    const ushort* Ap = A + (size_t)(m0 + sr) * 1024 + sk;
    // B staging: 8 n-values (bn8), k-pair bkp -> rows 2bkp, 2bkp+1
    const int bn8 = (t & 7) * 8, bkp = t >> 3;
    const ushort* Bp = Wb + (size_t)(2 * bkp) * 768 + n0 + bn8;

    uint4 av0 = *(const uint4*)(Ap);
    uint4 av1 = *(const uint4*)(Ap + 8);
    uint4 b0  = *(const uint4*)(Bp);
    uint4 b1  = *(const uint4*)(Bp + 768);

    for (int k0 = 0; k0 < 1024; k0 += 64) {
        *(uint4*)&As[sr][sk]     = av0;
        *(uint4*)&As[sr][sk + 8] = av1;
        {
            const ushort* s0 = (const ushort*)&b0;
            const ushort* s1 = (const ushort*)&b1;
            #pragma unroll
            for (int i = 0; i < 8; ++i)
                *(uint*)&Bs[bn8 + i][2 * bkp] = (uint)s0[i] | ((uint)s1[i] << 16);
        }
        __syncthreads();
        if (k0 + 64 < 1024) {   // register prefetch next k-step
            av0 = *(const uint4*)(Ap + k0 + 64);
            av1 = *(const uint4*)(Ap + k0 + 72);
            const ushort* Bn = Bp + (size_t)(k0 + 64) * 768;
            b0 = *(const uint4*)(Bn);
            b1 = *(const uint4*)(Bn + 768);
        }
        #pragma unroll
        for (int kk = 0; kk < 64; kk += 32) {
            const short8 a0 = *(const short8*)&As[wm + lrow][kk + lko];
            const short8 a1 = *(const short8*)&As[wm + 16 + lrow][kk + lko];
            const short8 bb0 = *(const short8*)&Bs[wn + lrow][kk + lko];
            const short8 bb1 = *(const short8*)&Bs[wn + 16 + lrow][kk + lko];
            acc[0][0] = MFMA_BF16(a0, bb0, acc[0][0], 0, 0, 0);
            acc[0][1] = MFMA_BF16(a0, bb1, acc[0][1], 0, 0, 0);
            acc[1][0] = MFMA_BF16(a1, bb0, acc[1][0], 0, 0, 0);
            acc[1][1] = MFMA_BF16(a1, bb1, acc[1][1], 0, 0, 0);
        }
        __syncthreads();
    }

    #pragma unroll
    for (int i = 0; i < 2; ++i)
        #pragma unroll
        for (int j = 0; j < 2; ++j)
            #pragma unroll
            for (int r = 0; r < 4; ++r) {
                const int m = m0 + wm + i * 16 + quad * 4 + r;
                const int n = n0 + wn + j * 16 + lrow;
                C[(size_t)m * 768 + n] = f2bf(acc[i][j][r]);
            }
}

// ---------------------------------------------------------------------------
// scores(bf16) = (qb @ kmb^T) / 32  [1024,256], 64 blocks (round-4 verbatim)
// ---------------------------------------------------------------------------
__global__ __launch_bounds__(256)
void scores_kernel(const ushort* __restrict__ qb, const ushort* __restrict__ kmb,
                   ushort* __restrict__ sc)
{
    __shared__ __align__(16) ushort As[64][72];
    __shared__ __align__(16) ushort Bs[64][72];

    const int t = threadIdx.x;
    const int m0 = blockIdx.y * 64, n0 = blockIdx.x * 64;
    const int wave = t >> 6, lane = t & 63;
    const int wm = (wave >> 1) * 32, wn = (wave & 1) * 32;
    const int lrow = lane & 15, quad = lane >> 4, lko = quad * 8;

    f32x4 acc[2][2];
    #pragma unroll
    for (int i = 0; i < 2; ++i)
        #pragma unroll
        for (int j = 0; j < 2; ++j) acc[i][j] = (f32x4)0.0f;

    const int sr = t >> 2, sk = (t & 3) << 4;
    const ushort* Ap = qb  + (size_t)(m0 + sr) * 768 + sk;
    const ushort* Bp = kmb + (size_t)(n0 + sr) * 768 + sk;

    uint4 av0 = *(const uint4*)(Ap);
    uint4 av1 = *(const uint4*)(Ap + 8);
    uint4 bv0 = *(const uint4*)(Bp);
    uint4 bv1 = *(const uint4*)(Bp + 8);

    for (int k0 = 0; k0 < 768; k0 += 64) {
        *(uint4*)&As[sr][sk]     = av0;
        *(uint4*)&As[sr][sk + 8] = av1;
        *(uint4*)&Bs[sr][sk]     = bv0;
        *(uint4*)&Bs[sr][sk + 8] = bv1;
        __syncthreads();
        if (k0 + 64 < 768) {
            av0 = *(const uint4*)(Ap + k0 + 64);
            av1 = *(const uint4*)(Ap + k0 + 72);
            bv0 = *(const uint4*)(Bp + k0 + 64);
            bv1 = *(const uint4*)(Bp + k0 + 72);
        }
        #pragma unroll
        for (int kk = 0; kk < 64; kk += 32) {
            const short8 a0 = *(const short8*)&As[wm + lrow][kk + lko];
            const short8 a1 = *(const short8*)&As[wm + 16 + lrow][kk + lko];
            const short8 b0 = *(const short8*)&Bs[wn + lrow][kk + lko];
            const short8 b1 = *(const short8*)&Bs[wn + 16 + lrow][kk + lko];
            acc[0][0] = MFMA_BF16(a0, b0, acc[0][0], 0, 0, 0);
            acc[0][1] = MFMA_BF16(a0, b1, acc[0][1], 0, 0, 0);
            acc[1][0] = MFMA_BF16(a1, b0, acc[1][0], 0, 0, 0);
            acc[1][1] = MFMA_BF16(a1, b1, acc[1][1], 0, 0, 0);
        }
        __syncthreads();
    }

    #pragma unroll
    for (int i = 0; i < 2; ++i)
        #pragma unroll
        for (int j = 0; j < 2; ++j)
            #pragma unroll
            for (int r = 0; r < 4; ++r) {
                const int m = m0 + wm + i * 16 + quad * 4 + r;
                const int n = n0 + wn + j * 16 + lrow;
                sc[(size_t)m * 256 + n] = f2bf(acc[i][j][r] * 0.03125f);
            }
}

// ---------------------------------------------------------------------------
// out = J + softmax(scores) @ cpT^T. Grid (16,16), 64x64 tile (round-4 verbatim)
// ---------------------------------------------------------------------------
__global__ __launch_bounds__(256)
void out_kernel(const ushort* __restrict__ sc, const ushort* __restrict__ cpT,
                const float* __restrict__ J, float* __restrict__ out)
{
    __shared__ __align__(16) ushort At[64][264];
    __shared__ __align__(16) ushort Bs[64][72];
    __shared__ float rowInv[64];

    const int t = threadIdx.x;
    const int m0 = blockIdx.y * 64, n0 = blockIdx.x * 64;

    {   // softmax prologue: 4 threads/row, unnormalized exp -> LDS bf16
        const int row = t >> 2;
        const int cb  = (t & 3) * 64;
        const ushort* srow = sc + (size_t)(m0 + row) * 256 + cb;
        uint4 s[8];
        #pragma unroll
        for (int i = 0; i < 8; ++i) s[i] = *(const uint4*)(srow + i * 8);

        float mx = -1e30f;
        #pragma unroll
        for (int i = 0; i < 8; ++i) {
            mx = fmaxf(mx, fmaxf(fmaxf(bflo(s[i].x), bfhi(s[i].x)),
                                 fmaxf(bflo(s[i].y), bfhi(s[i].y))));
            mx = fmaxf(mx, fmaxf(fmaxf(bflo(s[i].z), bfhi(s[i].z)),
                                 fmaxf(bflo(s[i].w), bfhi(s[i].w))));
        }
        mx = fmaxf(mx, __shfl_xor(mx, 1));
        mx = fmaxf(mx, __shfl_xor(mx, 2));

        float sum = 0.0f;
        #pragma unroll
        for (int i = 0; i < 8; ++i) {
            uint4 o;
            uint* su = (uint*)&s[i];
            uint* ou = (uint*)&o;
            #pragma unroll
            for (int w = 0; w < 4; ++w) {
                const ushort e0 = f2bf(__expf(bflo(su[w]) - mx));
                const ushort e1 = f2bf(__expf(bfhi(su[w]) - mx));
                sum += bflo((uint)e0) + bflo((uint)e1);
                ou[w] = (uint)e0 | ((uint)e1 << 16);
            }
            *(uint4*)&At[row][cb + i * 8] = o;
        }
        sum += __shfl_xor(sum, 1);
        sum += __shfl_xor(sum, 2);
        if ((t & 3) == 0) rowInv[row] = 1.0f / sum;
    }
    __syncthreads();

    const int wave = t >> 6, lane = t & 63;
    const int wm = (wave >> 1) * 32, wn = (wave & 1) * 32;
    const int lrow = lane & 15, quad = lane >> 4, lko = quad * 8;

    f32x4 acc[2][2];
    #pragma unroll
    for (int i = 0; i < 2; ++i)
        #pragma unroll
        for (int j = 0; j < 2; ++j) acc[i][j] = (f32x4)0.0f;

    const int sr = t >> 2, sk = (t & 3) << 4;
    const ushort* Bp = cpT + (size_t)(n0 + sr) * 256 + sk;
    uint4 bv0 = *(const uint4*)(Bp);
    uint4 bv1 = *(const uint4*)(Bp + 8);

    for (int k0 = 0; k0 < 256; k0 += 64) {
        *(uint4*)&Bs[sr][sk]     = bv0;
        *(uint4*)&Bs[sr][sk + 8] = bv1;
        __syncthreads();
        if (k0 + 64 < 256) {
            bv0 = *(const uint4*)(Bp + k0 + 64);
            bv1 = *(const uint4*)(Bp + k0 + 72);
        }
        #pragma unroll
        for (int kk = 0; kk < 64; kk += 32) {
            const short8 a0 = *(const short8*)&At[wm + lrow][k0 + kk + lko];
            const short8 a1 = *(const short8*)&At[wm + 16 + lrow][k0 + kk + lko];
            const short8 b0 = *(const short8*)&Bs[wn + lrow][kk + lko];
            const short8 b1 = *(const short8*)&Bs[wn + 16 + lrow][kk + lko];
            acc[0][0] = MFMA_BF16(a0, b0, acc[0][0], 0, 0, 0);
            acc[0][1] = MFMA_BF16(a0, b1, acc[0][1], 0, 0, 0);
            acc[1][0] = MFMA_BF16(a1, b0, acc[1][0], 0, 0, 0);
            acc[1][1] = MFMA_BF16(a1, b1, acc[1][1], 0, 0, 0);
        }
        __syncthreads();
    }

    #pragma unroll
    for (int i = 0; i < 2; ++i)
        #pragma unroll
        for (int j = 0; j < 2; ++j)
            #pragma unroll
            for (int r = 0; r < 4; ++r) {
                const int mrel = wm + i * 16 + quad * 4 + r;
                const int m = m0 + mrel;
                const int n = n0 + wn + j * 16 + lrow;
                const size_t off = (size_t)m * 1024 + n;
                out[off] = acc[i][j][r] * rowInv[mrel] + J[off];
            }
}

extern "C" void kernel_launch(void* const* d_in, const int* in_sizes, int n_in,
                              void* d_out, int out_size, void* d_ws, size_t ws_size,
                              hipStream_t stream)
{
    const float* J     = (const float*)d_in[0];
    const float* conf  = (const float*)d_in[1];
    const float* prior = (const float*)d_in[2];
    const float* Wq    = (const float*)d_in[3];
    const float* Wk    = (const float*)d_in[4];
    float* out = (float*)d_out;

    ushort* ws = (ushort*)d_ws;
    ushort* Jb    = ws;                  // 1024*1024
    ushort* confb = Jb    + 1048576;     // 256*1024
    ushort* Wqb   = confb + 262144;      // 1024*768 (NN)
    ushort* Wkb   = Wqb   + 786432;      // 1024*768 (NN)
    ushort* cpT   = Wkb   + 786432;      // 1024*256
    ushort* qb    = cpT   + 262144;      // 1024*768
    ushort* kmb   = qb    + 786432;      // 256*768
    ushort* scb   = kmb   + 196608;      // 1024*256 bf16 scores

    prep_kernel<<<3072, 256, 0, stream>>>(J, conf, prior, Wq, Wk,
                                          Jb, confb, Wqb, Wkb, cpT);
    qk_kernel<<<240, 256, 0, stream>>>(Jb, Wqb, confb, Wkb, qb, kmb);
    scores_kernel<<<dim3(4, 16), 256, 0, stream>>>(qb, kmb, scb);
    out_kernel<<<dim3(16, 16), 256, 0, stream>>>(scb, cpT, J, out);
}